// Round 1
// baseline (375.692 us; speedup 1.0000x reference)
//
#include <hip/hip_runtime.h>

#define BATCH 2
#define S_LEN 2048
#define NH 12
#define DMODEL 768
// DK = 64, scale = 1/8

typedef __attribute__((ext_vector_type(8))) short bf16x8;
typedef __attribute__((ext_vector_type(4))) float f32x4;
typedef __attribute__((ext_vector_type(4))) unsigned short us4;

__device__ __forceinline__ unsigned short f2bf(float f) {
  union { float f; unsigned int u; } v; v.f = f;
  unsigned int r = v.u + 0x7fffu + ((v.u >> 16) & 1u);  // RNE
  return (unsigned short)(r >> 16);
}

// ---------------- f32 -> bf16 convert (8 elems/thread) ----------------
__global__ void cvt_kernel(const float* __restrict__ src,
                           unsigned short* __restrict__ dst, int n8) {
  int i = blockIdx.x * blockDim.x + threadIdx.x;
  if (i >= n8) return;
  const float4* s = (const float4*)src;
  float4 a = s[i * 2], b = s[i * 2 + 1];
  us4 o0 = { f2bf(a.x), f2bf(a.y), f2bf(a.z), f2bf(a.w) };
  us4 o1 = { f2bf(b.x), f2bf(b.y), f2bf(b.z), f2bf(b.w) };
  us4* d = (us4*)dst;
  d[i * 2] = o0;
  d[i * 2 + 1] = o1;
}

#define GLD_LDS16(g, l)                                                    \
  __builtin_amdgcn_global_load_lds(                                        \
      (const __attribute__((address_space(1))) unsigned int*)(g),          \
      (__attribute__((address_space(3))) unsigned int*)(l), 16, 0, 0)

// ---------------- GEMM: C = A(M,K) @ B(N,K)^T, bf16 in, MFMA ----------
// MODE 0: bf16 row-major out, scaled.  MODE 1: bf16 V^T (B,H,64,S) out.
// MODE 2: f32 row-major out.
// Tile 128x64, BK=64, 256 threads (4 waves in 2x2), 16x16x32 bf16 MFMA.
template <int MODE>
__global__ __launch_bounds__(256, 2)
void gemm_bt(const unsigned short* __restrict__ A,
             const unsigned short* __restrict__ Bw,
             void* __restrict__ outp, int M, int N, int K, float scale) {
  __shared__ unsigned short As[128 * 64];
  __shared__ unsigned short Bs[64 * 64];
  const int m0 = blockIdx.x * 128, n0 = blockIdx.y * 64;
  const int tid = threadIdx.x, w = tid >> 6, l = tid & 63;
  const int lg = l >> 4, ll = l & 15;
  const int wm = w >> 1, wn = w & 1;
  const int lr = l >> 3, lc = (l & 7) * 8;

  f32x4 acc[4][2];
#pragma unroll
  for (int i = 0; i < 4; ++i)
#pragma unroll
    for (int j = 0; j < 2; ++j) acc[i][j] = (f32x4){0.f, 0.f, 0.f, 0.f};

  for (int k0 = 0; k0 < K; k0 += 64) {
#pragma unroll
    for (int i = 0; i < 4; ++i) {
      const unsigned short* src = A + (size_t)(m0 + w * 32 + i * 8 + lr) * K + k0 + lc;
      GLD_LDS16(src, &As[(w * 32 + i * 8) * 64]);
    }
#pragma unroll
    for (int i = 0; i < 2; ++i) {
      const unsigned short* src = Bw + (size_t)(n0 + w * 16 + i * 8 + lr) * K + k0 + lc;
      GLD_LDS16(src, &Bs[(w * 16 + i * 8) * 64]);
    }
    __syncthreads();
#pragma unroll
    for (int t = 0; t < 2; ++t) {
      bf16x8 af[4], bf[2];
#pragma unroll
      for (int mi = 0; mi < 4; ++mi)
        af[mi] = *(const bf16x8*)&As[(wm * 64 + mi * 16 + ll) * 64 + t * 32 + lg * 8];
#pragma unroll
      for (int ni = 0; ni < 2; ++ni)
        bf[ni] = *(const bf16x8*)&Bs[(wn * 32 + ni * 16 + ll) * 64 + t * 32 + lg * 8];
#pragma unroll
      for (int mi = 0; mi < 4; ++mi)
#pragma unroll
        for (int ni = 0; ni < 2; ++ni)
          acc[mi][ni] = __builtin_amdgcn_mfma_f32_16x16x32_bf16(
              af[mi], bf[ni], acc[mi][ni], 0, 0, 0);
    }
    __syncthreads();
  }

  // epilogue: C layout col = lane&15, row = (lane>>4)*4 + reg  [m89]
  if (MODE == 0) {
    unsigned short* o = (unsigned short*)outp;
#pragma unroll
    for (int mi = 0; mi < 4; ++mi)
#pragma unroll
      for (int ni = 0; ni < 2; ++ni) {
        const int col = n0 + wn * 32 + ni * 16 + ll;
        const int rowb = m0 + wm * 64 + mi * 16 + lg * 4;
#pragma unroll
        for (int r = 0; r < 4; ++r)
          o[(size_t)(rowb + r) * N + col] = f2bf(acc[mi][ni][r] * scale);
      }
  } else if (MODE == 1) {
    // V^T: feature col -> (h = col>>6, d = col&63); row -> (b, s)
    unsigned short* o = (unsigned short*)outp;
#pragma unroll
    for (int mi = 0; mi < 4; ++mi)
#pragma unroll
      for (int ni = 0; ni < 2; ++ni) {
        const int col = n0 + wn * 32 + ni * 16 + ll;
        const int row = m0 + wm * 64 + mi * 16 + lg * 4;
        const int bb = row >> 11, sidx = row & (S_LEN - 1);
        const size_t base =
            ((size_t)(bb * NH + (col >> 6)) * 64 + (col & 63)) * S_LEN + sidx;
        us4 pk = { f2bf(acc[mi][ni][0]), f2bf(acc[mi][ni][1]),
                   f2bf(acc[mi][ni][2]), f2bf(acc[mi][ni][3]) };
        *(us4*)&o[base] = pk;
      }
  } else {
    float* o = (float*)outp;
#pragma unroll
    for (int mi = 0; mi < 4; ++mi)
#pragma unroll
      for (int ni = 0; ni < 2; ++ni) {
        const int col = n0 + wn * 32 + ni * 16 + ll;
        const int rowb = m0 + wm * 64 + mi * 16 + lg * 4;
#pragma unroll
        for (int r = 0; r < 4; ++r)
          o[(size_t)(rowb + r) * N + col] = acc[mi][ni][r] * scale;
      }
  }
}

// ---------------- fused causal attention ----------------
// One WG per (q-tile pair, h, b). 4 waves; wave w owns rows qt*64+w*16..+16.
// Pass 1: online (m,l). Pass 2: recompute scores, write P f32 to d_out,
// LDS round-trip (XOR swizzle) -> bf16 A-frags, PV accumulate.
__global__ __launch_bounds__(256, 2)
void attn_fused(const unsigned short* __restrict__ Qp,
                const unsigned short* __restrict__ Kp,
                const unsigned short* __restrict__ VTp,
                float* __restrict__ attnw,
                unsigned short* __restrict__ ctx) {
  const int pairid = blockIdx.x, h = blockIdx.y, b = blockIdx.z;
  const int tid = threadIdx.x, w = tid >> 6, l = tid & 63;
  const int lg = l >> 4, ll = l & 15;
  __shared__ unsigned short plds[4][1024];  // 16x64 bf16 per wave
  char* plb = (char*)&plds[w][0];

  const unsigned short* kb = Kp + (size_t)b * S_LEN * DMODEL + h * 64;
  const unsigned short* vb = VTp + ((size_t)(b * NH + h)) * 64 * S_LEN;
  float* pbase = attnw + ((size_t)(b * NH + h)) * S_LEN * S_LEN;

  for (int half = 0; half < 2; ++half) {
    const int qt = (half == 0) ? pairid : 31 - pairid;  // balanced pairs
    const int q0 = qt * 64 + w * 16;
    const int nkt = qt + 1;

    bf16x8 qf[2];
    {
      const unsigned short* qb =
          Qp + (size_t)(b * S_LEN + q0 + ll) * DMODEL + h * 64 + lg * 8;
      qf[0] = *(const bf16x8*)qb;
      qf[1] = *(const bf16x8*)(qb + 32);
    }
    int rowg[4];
#pragma unroll
    for (int r = 0; r < 4; ++r) rowg[r] = q0 + lg * 4 + r;

    float m[4], lsum[4];
#pragma unroll
    for (int r = 0; r < 4; ++r) { m[r] = -1e30f; lsum[r] = 0.f; }

    // ---- pass 1: per-row max & sum (online) ----
    for (int kt = 0; kt < nkt; ++kt) {
      f32x4 s[4];
#pragma unroll
      for (int nb = 0; nb < 4; ++nb) s[nb] = (f32x4){0.f, 0.f, 0.f, 0.f};
#pragma unroll
      for (int t = 0; t < 2; ++t)
#pragma unroll
        for (int nb = 0; nb < 4; ++nb) {
          bf16x8 kf = *(const bf16x8*)(kb + (size_t)(kt * 64 + nb * 16 + ll) * DMODEL +
                                       t * 32 + lg * 8);
          s[nb] = __builtin_amdgcn_mfma_f32_16x16x32_bf16(qf[t], kf, s[nb], 0, 0, 0);
        }
      if (kt == nkt - 1) {  // diagonal tile: causal mask
#pragma unroll
        for (int nb = 0; nb < 4; ++nb) {
          const int col = kt * 64 + nb * 16 + ll;
#pragma unroll
          for (int r = 0; r < 4; ++r)
            if (col > rowg[r]) s[nb][r] = -1e30f;
        }
      }
      float tm[4], te[4], mn[4];
#pragma unroll
      for (int r = 0; r < 4; ++r)
        tm[r] = fmaxf(fmaxf(s[0][r], s[1][r]), fmaxf(s[2][r], s[3][r]));
#pragma unroll
      for (int off = 1; off < 16; off <<= 1)
#pragma unroll
        for (int r = 0; r < 4; ++r) tm[r] = fmaxf(tm[r], __shfl_xor(tm[r], off, 64));
#pragma unroll
      for (int r = 0; r < 4; ++r) {
        mn[r] = fmaxf(m[r], tm[r]);
        te[r] = __expf(s[0][r] - mn[r]) + __expf(s[1][r] - mn[r]) +
                __expf(s[2][r] - mn[r]) + __expf(s[3][r] - mn[r]);
      }
#pragma unroll
      for (int off = 1; off < 16; off <<= 1)
#pragma unroll
        for (int r = 0; r < 4; ++r) te[r] += __shfl_xor(te[r], off, 64);
#pragma unroll
      for (int r = 0; r < 4; ++r) {
        lsum[r] = lsum[r] * __expf(m[r] - mn[r]) + te[r];
        m[r] = mn[r];
      }
    }

    float linv[4];
#pragma unroll
    for (int r = 0; r < 4; ++r) linv[r] = 1.f / lsum[r];

    f32x4 cacc[4];
#pragma unroll
    for (int nb = 0; nb < 4; ++nb) cacc[nb] = (f32x4){0.f, 0.f, 0.f, 0.f};

    // ---- pass 2: recompute, write P, PV ----
    for (int kt = 0; kt < nkt; ++kt) {
      f32x4 s[4];
#pragma unroll
      for (int nb = 0; nb < 4; ++nb) s[nb] = (f32x4){0.f, 0.f, 0.f, 0.f};
#pragma unroll
      for (int t = 0; t < 2; ++t)
#pragma unroll
        for (int nb = 0; nb < 4; ++nb) {
          bf16x8 kf = *(const bf16x8*)(kb + (size_t)(kt * 64 + nb * 16 + ll) * DMODEL +
                                       t * 32 + lg * 8);
          s[nb] = __builtin_amdgcn_mfma_f32_16x16x32_bf16(qf[t], kf, s[nb], 0, 0, 0);
        }
#pragma unroll
      for (int nb = 0; nb < 4; ++nb) {
        const int col = kt * 64 + nb * 16 + ll;
#pragma unroll
        for (int r = 0; r < 4; ++r) {
          float p = (col <= rowg[r]) ? __expf(s[nb][r] - m[r]) * linv[r] : 0.f;
          pbase[(size_t)rowg[r] * S_LEN + col] = p;
          const int rl = lg * 4 + r;
          const int bo = ((rl * 64 + nb * 16 + ll) * 2) ^ ((rl & 7) << 4);
          *(unsigned short*)(plb + bo) = f2bf(p);
        }
      }
      __syncthreads();  // P tile visible (RAW)
      bf16x8 pf[2];
#pragma unroll
      for (int t = 0; t < 2; ++t) {
        const int bo = ((ll * 64 + t * 32 + lg * 8) * 2) ^ ((ll & 7) << 4);
        pf[t] = *(const bf16x8*)(plb + bo);
      }
#pragma unroll
      for (int t = 0; t < 2; ++t)
#pragma unroll
        for (int nb = 0; nb < 4; ++nb) {
          bf16x8 vf = *(const bf16x8*)(vb + (size_t)(nb * 16 + ll) * S_LEN +
                                       kt * 64 + t * 32 + lg * 8);
          cacc[nb] = __builtin_amdgcn_mfma_f32_16x16x32_bf16(pf[t], vf, cacc[nb], 0, 0, 0);
        }
      __syncthreads();  // WAR before next tile's writes
    }

    // ---- zero-fill masked columns (must overwrite 0xAA poison) ----
    const int zc = nkt * 64;
    for (int rr = 0; rr < 16; ++rr) {
      float* dst = pbase + (size_t)(qt * 64 + w * 16 + rr) * S_LEN;
      for (int c = zc + l * 4; c < S_LEN; c += 256)
        *(float4*)(dst + c) = make_float4(0.f, 0.f, 0.f, 0.f);
    }

    // ---- context write (bf16, (B,S,D) layout) ----
#pragma unroll
    for (int nb = 0; nb < 4; ++nb)
#pragma unroll
      for (int r = 0; r < 4; ++r)
        ctx[(size_t)(b * S_LEN + rowg[r]) * DMODEL + h * 64 + nb * 16 + ll] =
            f2bf(cacc[nb][r]);
  }
}

extern "C" void kernel_launch(void* const* d_in, const int* in_sizes, int n_in,
                              void* d_out, int out_size, void* d_ws, size_t ws_size,
                              hipStream_t stream) {
  const float* q_in = (const float*)d_in[0];
  const float* k_in = (const float*)d_in[1];
  const float* v_in = (const float*)d_in[2];
  // d_in[3] = mask: causal triu(k=1), hardcoded in attn kernel
  const float* wq = (const float*)d_in[4];
  const float* wk = (const float*)d_in[5];
  const float* wv = (const float*)d_in[6];
  const float* wo = (const float*)d_in[7];

  const int BSD = BATCH * S_LEN * DMODEL;  // 3145728
  const int DD = DMODEL * DMODEL;          // 589824
  const int M = BATCH * S_LEN;             // 4096

  char* ws = (char*)d_ws;
  unsigned short* qbf = (unsigned short*)ws;  ws += (size_t)BSD * 2;
  unsigned short* kbf = (unsigned short*)ws;  ws += (size_t)BSD * 2;
  unsigned short* vbf = (unsigned short*)ws;  ws += (size_t)BSD * 2;
  unsigned short* wqb = (unsigned short*)ws;  ws += (size_t)DD * 2;
  unsigned short* wkb = (unsigned short*)ws;  ws += (size_t)DD * 2;
  unsigned short* wvb = (unsigned short*)ws;  ws += (size_t)DD * 2;
  unsigned short* wob = (unsigned short*)ws;  ws += (size_t)DD * 2;
  unsigned short* Qs  = (unsigned short*)ws;  ws += (size_t)BSD * 2;
  unsigned short* Ks  = (unsigned short*)ws;  ws += (size_t)BSD * 2;
  unsigned short* VT  = (unsigned short*)ws;  ws += (size_t)BSD * 2;
  unsigned short* ctx = (unsigned short*)ws;  ws += (size_t)BSD * 2;

  float* out_proj = (float*)d_out;
  float* attnw = (float*)d_out + BSD;

  // f32 -> bf16
  cvt_kernel<<<BSD / 8 / 256, 256, 0, stream>>>(q_in, qbf, BSD / 8);
  cvt_kernel<<<BSD / 8 / 256, 256, 0, stream>>>(k_in, kbf, BSD / 8);
  cvt_kernel<<<BSD / 8 / 256, 256, 0, stream>>>(v_in, vbf, BSD / 8);
  cvt_kernel<<<DD / 8 / 256, 256, 0, stream>>>(wq, wqb, DD / 8);
  cvt_kernel<<<DD / 8 / 256, 256, 0, stream>>>(wk, wkb, DD / 8);
  cvt_kernel<<<DD / 8 / 256, 256, 0, stream>>>(wv, wvb, DD / 8);
  cvt_kernel<<<DD / 8 / 256, 256, 0, stream>>>(wo, wob, DD / 8);

  dim3 ggrid(M / 128, DMODEL / 64);  // 32 x 12
  // Q scaled by 1/sqrt(DK)=1/8 (exact pow2, folded into Q)
  gemm_bt<0><<<ggrid, 256, 0, stream>>>(qbf, wqb, Qs, M, DMODEL, DMODEL, 0.125f);
  gemm_bt<0><<<ggrid, 256, 0, stream>>>(kbf, wkb, Ks, M, DMODEL, DMODEL, 1.0f);
  gemm_bt<1><<<ggrid, 256, 0, stream>>>(vbf, wvb, VT, M, DMODEL, DMODEL, 1.0f);

  attn_fused<<<dim3(16, NH, BATCH), 256, 0, stream>>>(Qs, Ks, VT, attnw, ctx);

  gemm_bt<2><<<ggrid, 256, 0, stream>>>(ctx, wob, out_proj, M, DMODEL, DMODEL, 1.0f);
}